// Round 9
// baseline (820.560 us; speedup 1.0000x reference)
//
#include <hip/hip_runtime.h>
#include <hip/hip_bf16.h>

typedef short bf16x8 __attribute__((ext_vector_type(8)));
typedef float f32x4 __attribute__((ext_vector_type(4)));

#define B_ 128
#define T_ 64
#define F_ 2048
#define N_ 1024
#define H_ 1024
#define C_ 22

__device__ __forceinline__ ushort f2bf(float f) {
    union { float f; unsigned u; } v; v.f = f;
    unsigned u = v.u;
    unsigned r = (u + 0x7FFFu + ((u >> 16) & 1u)) >> 16;
    return (ushort)r;
}
__device__ __forceinline__ float bf2f(ushort h) {
    union { unsigned u; float f; } v; v.u = ((unsigned)h) << 16;
    return v.f;
}

// ---------------- fp32 -> bf16 convert (vectorized) ----------------
__global__ __launch_bounds__(256) void cvt_f32_bf16(const float* __restrict__ in,
                                                    ushort* __restrict__ out, int n4) {
    int i = blockIdx.x * blockDim.x + threadIdx.x;
    if (i < n4) {
        float4 v = ((const float4*)in)[i];
        ushort4 o;
        o.x = f2bf(v.x); o.y = f2bf(v.y); o.z = f2bf(v.z); o.w = f2bf(v.w);
        ((ushort4*)out)[i] = o;
    }
}

// Wc [22][1024] f32 -> [32][1024] bf16, zero-padded rows 22..31
__global__ __launch_bounds__(256) void cvt_wc(const float* __restrict__ Wc,
                                              ushort* __restrict__ Wcb) {
    int i = blockIdx.x * 256 + threadIdx.x;   // 32768 total
    int row = i >> 10;
    Wcb[i] = (row < C_) ? f2bf(Wc[i]) : (ushort)0;
}

// ---------------- async global->LDS, 16B per lane ----------------
__device__ __forceinline__ void gload16(const void* g, void* l) {
    __builtin_amdgcn_global_load_lds(
        (const __attribute__((address_space(1))) unsigned int*)g,
        (__attribute__((address_space(3))) unsigned int*)l, 16, 0, 0);
}

// ---------------- bf16 TN GEMM: C[m][n] = act(A[m][:] . B[n][:] + bias) ----------------
template<int K, bool RELU>
__global__ __launch_bounds__(256) void gemm_bt(const ushort* __restrict__ A,
                                               const ushort* __restrict__ Bm,
                                               const float* __restrict__ bias1,
                                               const float* __restrict__ bias2,
                                               ushort* __restrict__ C,
                                               int Nt, int Nn) {
    __shared__ ushort sA[128 * 32];
    __shared__ ushort sB[128 * 32];
    const int tid = threadIdx.x;
    const int lane = tid & 63, wv = tid >> 6;
    const int tm = blockIdx.x / Nt, tn = blockIdx.x % Nt;
    const int wm = wv >> 1, wn = wv & 1;

    const ushort* gA = A + (size_t)(tm * 128 + (tid >> 2)) * K + (tid & 3) * 8;
    const ushort* gB = Bm + (size_t)(tn * 128 + (tid >> 2)) * K + (tid & 3) * 8;
    char* lAb = (char*)sA + wv * 1024;
    char* lBb = (char*)sB + wv * 1024;

    f32x4 acc[4][4] = {};

    for (int kt = 0; kt < K / 32; kt++) {
        const ushort* a0 = gA + kt * 32;
        const ushort* b0 = gB + kt * 32;
        gload16(a0, lAb);
        gload16(a0 + 64 * K, lAb + 4096);
        gload16(b0, lBb);
        gload16(b0 + 64 * K, lBb + 4096);
        __syncthreads();

        bf16x8 af[4], bfv[4];
#pragma unroll
        for (int i = 0; i < 4; i++)
            af[i] = *(const bf16x8*)&sA[(wm * 64 + i * 16 + (lane & 15)) * 32 + (lane >> 4) * 8];
#pragma unroll
        for (int j = 0; j < 4; j++)
            bfv[j] = *(const bf16x8*)&sB[(wn * 64 + j * 16 + (lane & 15)) * 32 + (lane >> 4) * 8];
#pragma unroll
        for (int i = 0; i < 4; i++)
#pragma unroll
            for (int j = 0; j < 4; j++)
                acc[i][j] = __builtin_amdgcn_mfma_f32_16x16x32_bf16(af[i], bfv[j], acc[i][j], 0, 0, 0);
        __syncthreads();
    }

#pragma unroll
    for (int j = 0; j < 4; j++) {
        int n = tn * 128 + wn * 64 + j * 16 + (lane & 15);
        float bias = bias1[n] + (bias2 ? bias2[n] : 0.f);
#pragma unroll
        for (int i = 0; i < 4; i++) {
            int mbase = tm * 128 + wm * 64 + i * 16 + (lane >> 4) * 4;
#pragma unroll
            for (int r = 0; r < 4; r++) {
                float v = acc[i][j][r] + bias;
                if (RELU) v = v > 0.f ? v : 0.f;
                C[(size_t)(mbase + r) * Nn + n] = f2bf(v);
            }
        }
    }
}

// ---------- persistent LSTM recurrence: 512-thr blocks (2 waves/SIMD), XCD-local groups ----------
// 256 blocks x 512 thr, 1 block/CU (launch_bounds(512,2): 8 waves = 2/SIMD -> latency hiding).
// blk = hb*8 + bt: bt = batch-tile of 16 rows, hb = 32-col hid tile. All 32 blocks of a
// group share (blk&7) -> same XCD under round-robin dispatch (heuristic: L2-local h/flag
// exchange; correctness never depends on it -- agent-scope protocol as proven in round 3).
// Wave w: gate g=w>>1, col-half ch=w&1. Weights: 32 x bf16x8 per lane (same as round 3).
__global__ __launch_bounds__(512, 2) void lstm_persist(ushort* __restrict__ hs,
                                                       const ushort* __restrict__ xg,
                                                       const ushort* __restrict__ Whh,
                                                       unsigned* __restrict__ flags) {
    const int tid = threadIdx.x;
    const int lane = tid & 63;
    const int wv = tid >> 6;                 // 0..7
    const int g = wv >> 1;                   // gate
    const int ch = wv & 1;                   // col half (16 cols)
    const int blk = (int)blockIdx.x;
    const int bt = blk & 7;                  // batch tile (16 rows) == XCD id (heuristic)
    const int hb = blk >> 3;                 // hid tile (32 cols)
    const int batch0 = bt * 16;
    const int hid0 = hb * 32;

    // Whh B-fragments: rows g*H + hid0 + ch*16 + (lane&15), k = (lane>>4)*8 + ks*32
    bf16x8 breg[32];
    {
        const ushort* br = Whh + (size_t)(g * H_ + hid0 + ch * 16 + (lane & 15)) * H_
                         + ((lane >> 4) * 8);
#pragma unroll
        for (int ks = 0; ks < 32; ks++) breg[ks] = *(const bf16x8*)(br + ks * 32);
#pragma unroll
        for (int ks = 0; ks < 32; ks++) asm volatile("" : "+v"(breg[ks]));
    }

    __shared__ float lg[4][16][32];          // [gate][batch row][hid col], read conflict-free

    const int grow = tid >> 5;               // 0..15 batch row within tile
    const int gcol = tid & 31;               // 0..31 hid col within tile
    const int b = batch0 + grow;
    const int jj = hid0 + gcol;
    const ushort* xrow = xg + ((size_t)(b * T_) << 12) + jj;   // advance 4096/step
    float c0 = 0.f;

    for (int t = 0; t < T_; t++) {
        // xg loads issued early (HBM latency hides under h-load + MFMA)
        const ushort* xr = xrow + ((size_t)t << 12);
        ushort xi = xr[0], xf = xr[1024], xgv = xr[2048], xo = xr[3072];

        // gates_pre = h[t](16 rows) @ Whh_tile^T
        const ushort* ar = hs + (size_t)t * (B_ * H_)
                         + (size_t)(batch0 + (lane & 15)) * H_ + ((lane >> 4) * 8);
        f32x4 acc = {};
#pragma unroll
        for (int ks = 0; ks < 32; ks++) {
            bf16x8 a0 = *(const bf16x8*)(ar + ks * 32);
            acc = __builtin_amdgcn_mfma_f32_16x16x32_bf16(a0, breg[ks], acc, 0, 0, 0);
        }
#pragma unroll
        for (int r = 0; r < 4; r++)
            lg[g][(lane >> 4) * 4 + r][ch * 16 + (lane & 15)] = acc[r];
        __syncthreads();

        // gate math: 1 (row,col) cell per thread
        {
            float pi = bf2f(xi)  + lg[0][grow][gcol];
            float pf = bf2f(xf)  + lg[1][grow][gcol];
            float pg = bf2f(xgv) + lg[2][grow][gcol];
            float po = bf2f(xo)  + lg[3][grow][gcol];
            float si = 1.f / (1.f + expf(-pi));
            float sf = 1.f / (1.f + expf(-pf));
            float tg = tanhf(pg);
            float so = 1.f / (1.f + expf(-po));
            c0 = sf * c0 + si * tg;
            ushort hbf = f2bf(so * tanhf(c0));
            uint other = __shfl_xor((uint)hbf, 1);           // neighbor col^1 (same wave)
            if ((lane & 1) == 0) {
                uint hp = (uint)hbf | (other << 16);
                unsigned* hp32 = (unsigned*)(hs + (size_t)(t + 1) * (B_ * H_)
                                             + (size_t)b * H_ + jj);
                // agent-scope store: write-through (L2+L3), visible to all XCDs
                __hip_atomic_store(hp32, hp, __ATOMIC_RELAXED, __HIP_MEMORY_SCOPE_AGENT);
            }
        }
        __syncthreads();   // per-wave vmcnt(0) before s_barrier -> all h stores drained

        if (t < T_ - 1) {
            if (tid == 0)
                __hip_atomic_store(&flags[blk * 16], (unsigned)(t + 1),
                                   __ATOMIC_RELAXED, __HIP_MEMORY_SCOPE_AGENT);
            if (wv == 0) {
                asm volatile("s_waitcnt vmcnt(0)" ::: "memory");
                for (;;) {
                    // poll the 32 flags of this batch-tile group (blocks hb'*8 + bt)
                    unsigned f = __hip_atomic_load(&flags[((lane & 31) * 8 + bt) * 16],
                                                   __ATOMIC_RELAXED, __HIP_MEMORY_SCOPE_AGENT);
                    if (__ballot(f < (unsigned)(t + 1)) == 0ull) break;
                    __builtin_amdgcn_s_sleep(1);
                }
            }
            __syncthreads();
        }
    }
}

// ---------------- final classifier via MFMA: out[8192][22] = hs @ Wcb^T + bc ----------------
__global__ __launch_bounds__(256) void scores_mfma(const ushort* __restrict__ hs,
                                                   const ushort* __restrict__ Wcb,
                                                   const float* __restrict__ bc,
                                                   float* __restrict__ out) {
    const int tid = threadIdx.x, lane = tid & 63, w = tid >> 6;
    const int r0 = blockIdx.x * 64 + w * 16;
    const int rr = r0 + (lane & 15);          // output row = b*64 + t
    const int b = rr >> 6, t = rr & 63;
    const ushort* arow = hs + (size_t)(t + 1) * (B_ * H_) + (size_t)b * H_ + ((lane >> 4) * 8);
    const ushort* brow0 = Wcb + (size_t)(lane & 15) * H_ + ((lane >> 4) * 8);
    const ushort* brow1 = brow0 + 16 * H_;

    f32x4 acc0 = {}, acc1 = {};
#pragma unroll
    for (int ks = 0; ks < 32; ks++) {
        bf16x8 a  = *(const bf16x8*)(arow + ks * 32);
        bf16x8 p0 = *(const bf16x8*)(brow0 + ks * 32);
        bf16x8 p1 = *(const bf16x8*)(brow1 + ks * 32);
        acc0 = __builtin_amdgcn_mfma_f32_16x16x32_bf16(a, p0, acc0, 0, 0, 0);
        acc1 = __builtin_amdgcn_mfma_f32_16x16x32_bf16(a, p1, acc1, 0, 0, 0);
    }
#pragma unroll
    for (int nf = 0; nf < 2; nf++) {
        int c = nf * 16 + (lane & 15);
        if (c < C_) {
            float bias = bc[c];
            f32x4 acc = nf ? acc1 : acc0;
#pragma unroll
            for (int r = 0; r < 4; r++) {
                int row = r0 + (lane >> 4) * 4 + r;
                out[(size_t)row * C_ + c] = acc[r] + bias;
            }
        }
    }
}

extern "C" void kernel_launch(void* const* d_in, const int* in_sizes, int n_in,
                              void* d_out, int out_size, void* d_ws, size_t ws_size,
                              hipStream_t stream) {
    const float* x = (const float*)d_in[0];
    const float* W1 = (const float*)d_in[1];
    const float* b1 = (const float*)d_in[2];
    const float* W_ih = (const float*)d_in[3];
    const float* b_ih = (const float*)d_in[4];
    const float* W_hh = (const float*)d_in[5];
    const float* b_hh = (const float*)d_in[6];
    const float* Wc = (const float*)d_in[7];
    const float* bc = (const float*)d_in[8];
    float* out = (float*)d_out;

    char* ws = (char*)d_ws;
    ushort* Xb   = (ushort*)(ws);                 // 33,554,432 B  [8192][2048] bf16
    ushort* W1b  = (ushort*)(ws + 33554432);      //  4,194,304 B
    ushort* Wihb = (ushort*)(ws + 37748736);      //  8,388,608 B
    ushort* Whhb = (ushort*)(ws + 46137344);      //  8,388,608 B
    ushort* z    = (ushort*)(ws + 54525952);      // 16,777,216 B  [8192][1024]
    ushort* xg   = (ushort*)(ws + 71303168);      // 67,108,864 B  [8192][4096]
    ushort* hs   = (ushort*)(ws + 138412032);     // 17,039,360 B  [65][128][1024]
    ushort* Wcb  = (ushort*)(ws + 155451392);     //     65,536 B  [32][1024] bf16
    unsigned* flags = (unsigned*)(ws + 155516928);//     16,384 B  [256] padded u32 (64B/flag)
    // total ws use: ~155.5 MB

    hipMemsetAsync(hs, 0, (size_t)B_ * H_ * sizeof(ushort), stream);   // h0 = 0
    hipMemsetAsync(flags, 0, 16384, stream);                           // barrier flags = 0

    cvt_f32_bf16<<<16384, 256, 0, stream>>>(x, Xb, 4194304);
    cvt_f32_bf16<<<2048, 256, 0, stream>>>(W1, W1b, 524288);
    cvt_f32_bf16<<<4096, 256, 0, stream>>>(W_ih, Wihb, 1048576);
    cvt_f32_bf16<<<4096, 256, 0, stream>>>(W_hh, Whhb, 1048576);
    cvt_wc<<<128, 256, 0, stream>>>(Wc, Wcb);

    // z = relu(x @ W1^T + b1)                 M=8192 N=1024 K=2048
    gemm_bt<2048, true><<<512, 256, 0, stream>>>(Xb, W1b, b1, nullptr, z, 8, 1024);
    // xg = z @ W_ih^T + (b_ih + b_hh)         M=8192 N=4096 K=1024
    gemm_bt<1024, false><<<2048, 256, 0, stream>>>(z, Wihb, b_ih, b_hh, xg, 32, 4096);

    // recurrence: 256 blocks x 512 thr, 1 blk/CU, 2 waves/SIMD, XCD-local groups
    lstm_persist<<<256, 512, 0, stream>>>(hs, xg, Whhb, flags);

    scores_mfma<<<128, 256, 0, stream>>>(hs, Wcb, bc, out);
}